// Round 8
// baseline (355.125 us; speedup 1.0000x reference)
//
#include <hip/hip_runtime.h>

// MHA forward, bf16-MFMA pipeline.
// ws: xb(16M) | Wqkv_t(6M) | Wo_t(2M) | Q(16M) | K(16M) | Vt(16M) | AO(16M)

typedef short short8 __attribute__((ext_vector_type(8)));
typedef float f32x4 __attribute__((ext_vector_type(4)));
typedef float f32x16 __attribute__((ext_vector_type(16)));

#define DMODEL 1024
#define NH 16
#define DK 64
#define SEQ 2048
#define NB 4
#define MTOT (NB*SEQ)   // 8192
// 1/sqrt(dk) * log2(e)  — folded into K at projection time; softmax runs in exp2 domain
#define KSCALE 0.18033688f

__device__ __forceinline__ unsigned short f2bf(float f) {
    union { float f; unsigned u; } v; v.f = f;
    unsigned r = (v.u + 0x7FFFu + ((v.u >> 16) & 1u)) >> 16;  // RNE
    return (unsigned short)r;
}

__device__ __forceinline__ unsigned pk2(float a, float b) {
    unsigned r;
    asm("v_cvt_pk_bf16_f32 %0, %1, %2" : "=v"(r) : "v"(a), "v"(b));
    return r;
}

__device__ __forceinline__ float exp2a(float x) {
    float r; asm("v_exp_f32 %0, %1" : "=v"(r) : "v"(x)); return r;
}

__device__ __forceinline__ float max3a(float a, float b, float c) {
    float r; asm("v_max3_f32 %0, %1, %2, %3" : "=v"(r) : "v"(a), "v"(b), "v"(c)); return r;
}

// v_permlane32_swap_b32: vdst lanes 32-63 <-> vsrc lanes 0-31 (both modified)
__device__ __forceinline__ void plswap(unsigned &a, unsigned &b) {
    asm volatile("v_permlane32_swap_b32 %0, %1" : "+v"(a), "+v"(b));
}

// async global->LDS, 16B per lane; lds dest is wave-uniform base (+lane*16)
__device__ __forceinline__ void gload16(const short* g, short* l) {
    __builtin_amdgcn_global_load_lds(
        (const __attribute__((address_space(1))) unsigned*)(const void*)g,
        (__attribute__((address_space(3))) unsigned*)(void*)l,
        16, 0, 0);
}

__device__ __forceinline__ void vm8()   { asm volatile("s_waitcnt vmcnt(8)"   ::: "memory"); }
__device__ __forceinline__ void vm4()   { asm volatile("s_waitcnt vmcnt(4)"   ::: "memory"); }
__device__ __forceinline__ void vm0()   { asm volatile("s_waitcnt vmcnt(0)"   ::: "memory"); }
__device__ __forceinline__ void lgkm0() { asm volatile("s_waitcnt lgkmcnt(0)" ::: "memory"); }

union Frag { short8 s8; unsigned u[4]; };

// ---------- fused prep: x fp32->bf16 convert + 4x W transpose ----------
#define NCVT (MTOT * DMODEL / 4 / 256)   // 8192
__global__ __launch_bounds__(256) void prep_kernel(
    const float* __restrict__ x, short* __restrict__ xb,
    const float* __restrict__ Wq, const float* __restrict__ Wk,
    const float* __restrict__ Wv, const float* __restrict__ Wo,
    short* __restrict__ Wqkvt, short* __restrict__ Wot)
{
    __shared__ float t[32][33];
    int bid = blockIdx.x;
    if (bid < NCVT) {
        int i = bid * 256 + threadIdx.x;
        float4 v = ((const float4*)x)[i];
        short4 o;
        o.x = (short)f2bf(v.x); o.y = (short)f2bf(v.y);
        o.z = (short)f2bf(v.z); o.w = (short)f2bf(v.w);
        ((short4*)xb)[i] = o;
        return;
    }
    int wb = bid - NCVT;                 // 0..4095
    int widx = wb >> 10, tile = wb & 1023;
    const float* W = (widx == 0) ? Wq : (widx == 1) ? Wk : (widx == 2) ? Wv : Wo;
    short* dst = (widx < 3) ? (Wqkvt + (size_t)widx * DMODEL * DMODEL) : Wot;
    int r0 = (tile >> 5) * 32, c0 = (tile & 31) * 32;
    int tr = threadIdx.x >> 3;
    int tc = (threadIdx.x & 7) * 4;
    float4 v = *(const float4*)&W[(r0 + tr) * DMODEL + c0 + tc];
    t[tr][tc + 0] = v.x; t[tr][tc + 1] = v.y; t[tr][tc + 2] = v.z; t[tr][tc + 3] = v.w;
    __syncthreads();
    short4 o;
    o.x = (short)f2bf(t[tc + 0][tr]);
    o.y = (short)f2bf(t[tc + 1][tr]);
    o.z = (short)f2bf(t[tc + 2][tr]);
    o.w = (short)f2bf(t[tc + 3][tr]);
    *(short4*)&dst[(c0 + tr) * DMODEL + r0 + tc] = o;
}

// ---------- 128x128 bf16 GEMM, counted-vmcnt 2-phase pipeline (proven R6) ----------
// + bijective XCD chunk swizzle on the flat block index (T1).
template<int MODE>
__global__ __launch_bounds__(256) void gemm_kernel(
    const short* __restrict__ A, const short* __restrict__ Bt,
    const float* __restrict__ b0, const float* __restrict__ b1, const float* __restrict__ b2,
    short* __restrict__ Qb, short* __restrict__ Kb, short* __restrict__ Vtb,
    float* __restrict__ Cout)
{
    __shared__ __align__(16) short L[2][2][2][128 * 32];   // [buf][A/B][kkh][r*32+c]
    const int K = DMODEL;
    const int NKT = K / 64;   // 16
    // XCD swizzle: nwg divisible by 8 for both launches -> bijective chunk map
    int nx = gridDim.x;
    int nwg = nx * gridDim.y;
    int flat = blockIdx.y * nx + blockIdx.x;
    int qch = nwg >> 3;
    int swz = (flat & 7) * qch + (flat >> 3);
    int m0 = (swz / nx) * 128, n0 = (swz % nx) * 128;
    int tid = threadIdx.x, lane = tid & 63, wid = tid >> 6;
    int wm = (wid >> 1) * 64, wn = (wid & 1) * 64;

    int srowl = (lane >> 2);
    int scoll = ((lane & 3) ^ ((lane >> 3) & 3)) * 8;
    const short* aSrc = A + (size_t)(m0 + wid * 32 + srowl) * K + scoll;
    const short* bSrc = Bt + (size_t)(n0 + wid * 32 + srowl) * K + scoll;

    f32x4 acc[4][4];
    #pragma unroll
    for (int i = 0; i < 4; i++)
        #pragma unroll
        for (int j = 0; j < 4; j++) acc[i][j] = (f32x4){0.f, 0.f, 0.f, 0.f};

    auto STAGE = [&](int kt, int kkh) {
        int buf = kt & 1;
        const short* as = aSrc + (size_t)kt * 64 + kkh * 32;
        const short* bs = bSrc + (size_t)kt * 64 + kkh * 32;
        #pragma unroll
        for (int i = 0; i < 2; ++i) {
            gload16(as + (size_t)i * 16 * K, &L[buf][0][kkh][(wid * 32 + i * 16) * 32]);
            gload16(bs + (size_t)i * 16 * K, &L[buf][1][kkh][(wid * 32 + i * 16) * 32]);
        }
    };
    auto LDA = [&](int buf, int kkh, short8* f) {
        #pragma unroll
        for (int m = 0; m < 4; m++) {
            int r = wm + m * 16 + (lane & 15);
            f[m] = *(const short8*)&L[buf][0][kkh][r * 32 + (((lane >> 4) ^ ((r >> 1) & 3)) * 8)];
        }
    };
    auto LDB = [&](int buf, int kkh, short8* f) {
        #pragma unroll
        for (int n = 0; n < 4; n++) {
            int r = wn + n * 16 + (lane & 15);
            f[n] = *(const short8*)&L[buf][1][kkh][r * 32 + (((lane >> 4) ^ ((r >> 1) & 3)) * 8)];
        }
    };

    STAGE(0, 0);
    STAGE(0, 1);
    STAGE(1, 0);
    vm8();
    __builtin_amdgcn_s_barrier();

    for (int k = 0; k < NKT; ++k) {
        int buf = k & 1;
        {
            short8 af[4], bfv[4];
            LDA(buf, 0, af); LDB(buf, 0, bfv);
            if (k + 1 < NKT) STAGE(k + 1, 1);
            lgkm0();
            __builtin_amdgcn_s_barrier();
            __builtin_amdgcn_s_setprio(1);
            #pragma unroll
            for (int i = 0; i < 4; i++)
                #pragma unroll
                for (int j = 0; j < 4; j++)
                    acc[i][j] = __builtin_amdgcn_mfma_f32_16x16x32_bf16(af[i], bfv[j], acc[i][j], 0, 0, 0);
            __builtin_amdgcn_s_setprio(0);
            if (k == NKT - 1) vm0(); else vm8();
            __builtin_amdgcn_s_barrier();
        }
        {
            short8 af[4], bfv[4];
            LDA(buf, 1, af); LDB(buf, 1, bfv);
            if (k + 2 < NKT) STAGE(k + 2, 0);
            lgkm0();
            __builtin_amdgcn_s_barrier();
            __builtin_amdgcn_s_setprio(1);
            #pragma unroll
            for (int i = 0; i < 4; i++)
                #pragma unroll
                for (int j = 0; j < 4; j++)
                    acc[i][j] = __builtin_amdgcn_mfma_f32_16x16x32_bf16(af[i], bfv[j], acc[i][j], 0, 0, 0);
            __builtin_amdgcn_s_setprio(0);
            if (k < NKT - 1) {
                if (k == NKT - 2) vm4(); else vm8();
                __builtin_amdgcn_s_barrier();
            }
        }
    }

    #pragma unroll
    for (int i = 0; i < 4; i++) {
        #pragma unroll
        for (int j = 0; j < 4; j++) {
            int col = n0 + wn + j * 16 + (lane & 15);
            #pragma unroll
            for (int r = 0; r < 4; r++) {
                int row = m0 + wm + i * 16 + (lane >> 4) * 4 + r;
                float v = acc[i][j][r];
                if (MODE == 0) {
                    int seg = col >> 10, c = col & 1023;
                    const float* bp = (seg == 0) ? b0 : (seg == 1 ? b1 : b2);
                    v += bp[c];
                    if (seg == 1) v *= KSCALE;   // fold softmax scale*log2e into K
                    unsigned short bv = f2bf(v);
                    int hh = c >> 6, d = c & 63, bb = row >> 11, s = row & 2047;
                    if (seg == 0)      Qb [(((bb * NH + hh) * SEQ) + s) * DK + d] = (short)bv;
                    else if (seg == 1) Kb [(((bb * NH + hh) * SEQ) + s) * DK + d] = (short)bv;
                    else               Vtb[(((bb * NH + hh) * DK) + d) * SEQ + s] = (short)bv;
                } else {
                    Cout[row * DMODEL + col] = v + b0[col];
                }
            }
        }
    }
}

// ---------- flash attention, swapped-QK^T 32x32, NO LDS (direct-from-L2) ----------
// K-tile (8KB) and Vt-tile (8KB) are L2/L1-resident (re-read by 16 q-blocks);
// A-operand fragments load straight from global: lane pair (l,l+32) reads
// adjacent 16B of row l31. No barriers, no staging — waves run free.
// Softmax: exp2 domain (KSCALE folded into K), max3 tree + defer-max (R6-proven).
__global__ __launch_bounds__(256) void attn_kernel(
    const short* __restrict__ Qb, const short* __restrict__ Kb,
    const short* __restrict__ Vtb, short* __restrict__ AOb)
{
    int bid = blockIdx.x;                       // 0..1023
    int wk = (bid & 7) * 128 + (bid >> 3);      // XCD-contiguous work
    int qi = wk & 15, bh = wk >> 4;
    int h = bh & (NH - 1), b = bh >> 4;
    int q0 = qi * 128;

    int tid = threadIdx.x, lane = tid & 63, wid = tid >> 6;
    int hi = lane >> 5, l31 = lane & 31;
    const short* Qp = Qb + (size_t)bh * SEQ * DK;
    // per-lane fragment bases: row l31, byte offset hi*16
    const short* Kp = Kb + (size_t)bh * SEQ * DK + (size_t)l31 * DK + hi * 8;
    const short* Vp = Vtb + (size_t)bh * DK * SEQ + (size_t)l31 * SEQ + hi * 8;

    // Q fragments (B-operand): lane holds Q[q=l31][ks*16+hi*8+j]
    short8 qf[4];
    #pragma unroll
    for (int ks = 0; ks < 4; ks++)
        qf[ks] = *(const short8*)&Qp[(q0 + wid * 32 + l31) * DK + ks * 16 + hi * 8];

    f32x16 ot0, ot1;
    #pragma unroll
    for (int r = 0; r < 16; r++) { ot0[r] = 0.f; ot1[r] = 0.f; }
    float mrun = -1e30f, lrun = 0.f;

    const int NT = SEQ / 64;
    for (int t = 0; t < NT; ++t) {
        // K fragments direct from global (L1/L2-hit)
        const short* kt = Kp + (size_t)t * 64 * DK;
        short8 kf0[4], kf1[4];
        #pragma unroll
        for (int ks = 0; ks < 4; ks++) {
            kf0[ks] = *(const short8*)&kt[ks * 16];
            kf1[ks] = *(const short8*)&kt[32 * DK + ks * 16];
        }

        // swapped QK^T: St[kv][q]
        f32x16 st0, st1;
        #pragma unroll
        for (int r = 0; r < 16; r++) { st0[r] = 0.f; st1[r] = 0.f; }
        __builtin_amdgcn_s_setprio(1);
        #pragma unroll
        for (int ks = 0; ks < 4; ks++) {
            st0 = __builtin_amdgcn_mfma_f32_32x32x16_bf16(kf0[ks], qf[ks], st0, 0, 0, 0);
            st1 = __builtin_amdgcn_mfma_f32_32x32x16_bf16(kf1[ks], qf[ks], st1, 0, 0, 0);
        }
        __builtin_amdgcn_s_setprio(0);

        // V fragments issued now — latency hides under softmax (~250 cyc)
        const short* vt = Vp + t * 64;
        short8 vf0[4], vf1[4];
        #pragma unroll
        for (int ks = 0; ks < 4; ks++) {
            vf0[ks] = *(const short8*)&vt[ks * 16];
            vf1[ks] = *(const short8*)&vt[32 * SEQ + ks * 16];
        }

        // row max via max3 tree (32 values -> 1), then lane-pair exchange
        float m8[8];
        #pragma unroll
        for (int i = 0; i < 8; i++) m8[i] = max3a(st0[i], st0[i + 8], st1[i]);
        float m4[4];
        #pragma unroll
        for (int i = 0; i < 4; i++) m4[i] = max3a(m8[i], m8[i + 4], st1[i + 8]);
        float m2a = max3a(m4[0], m4[2], st1[12]);
        float m2b = max3a(m4[1], m4[3], st1[13]);
        float mxv = max3a(m2a, m2b, st1[14]);
        mxv = fmaxf(mxv, st1[15]);
        float mt = fmaxf(mxv, __shfl_xor(mxv, 32, 64));

        // T13 defer-max (log2 domain, threshold 11 -> P bounded by 2^11)
        if (!__all(mt - mrun <= 11.0f)) {
            float mn = fmaxf(mrun, mt);
            float al = exp2a(mrun - mn);
            lrun *= al;
            #pragma unroll
            for (int r = 0; r < 16; r++) { ot0[r] *= al; ot1[r] *= al; }
            mrun = mn;
        }
        #pragma unroll
        for (int r = 0; r < 16; r++) {
            st0[r] = exp2a(st0[r] - mrun);
            st1[r] = exp2a(st1[r] - mrun);
        }
        float s16[16];
        #pragma unroll
        for (int r = 0; r < 16; r++) s16[r] = st0[r] + st1[r];
        #pragma unroll
        for (int s = 8; s > 0; s >>= 1)
            #pragma unroll
            for (int r = 0; r < 8; r++) if (r < s) s16[r] += s16[r + s];
        lrun += s16[0] + __shfl_xor(s16[0], 32, 64);

        // T12 repack: P -> bf16 B-fragments via cvt_pk + permlane32_swap
        unsigned w0[8], w1[8];
        #pragma unroll
        for (int m = 0; m < 4; m++) {
            w0[m * 2]     = pk2(st0[4 * m], st0[4 * m + 1]);
            w0[m * 2 + 1] = pk2(st0[4 * m + 2], st0[4 * m + 3]);
            w1[m * 2]     = pk2(st1[4 * m], st1[4 * m + 1]);
            w1[m * 2 + 1] = pk2(st1[4 * m + 2], st1[4 * m + 3]);
        }
        short8 pf[4];
        #pragma unroll
        for (int ks = 0; ks < 4; ks++) {
            unsigned a0 = (ks < 2) ? w0[4 * (ks & 1) + 0] : w1[4 * (ks & 1) + 0];
            unsigned b0_ = (ks < 2) ? w0[4 * (ks & 1) + 2] : w1[4 * (ks & 1) + 2];
            unsigned a1 = (ks < 2) ? w0[4 * (ks & 1) + 1] : w1[4 * (ks & 1) + 1];
            unsigned b1_ = (ks < 2) ? w0[4 * (ks & 1) + 3] : w1[4 * (ks & 1) + 3];
            plswap(a0, b0_);
            plswap(a1, b1_);
            Frag f;
            f.u[0] = a0; f.u[1] = a1; f.u[2] = b0_; f.u[3] = b1_;
            pf[ks] = f.s8;
        }

        // transposed PV: O^T[d][q] += V^T * P^T
        __builtin_amdgcn_s_setprio(1);
        #pragma unroll
        for (int ks = 0; ks < 4; ks++) {
            ot0 = __builtin_amdgcn_mfma_f32_32x32x16_bf16(vf0[ks], pf[ks], ot0, 0, 0, 0);
            ot1 = __builtin_amdgcn_mfma_f32_32x32x16_bf16(vf1[ks], pf[ks], ot1, 0, 0, 0);
        }
        __builtin_amdgcn_s_setprio(0);
    }

    // epilogue: normalize + store O[q][d] bf16 into AOb[b*SEQ+s][h*64+d]
    float inv = 1.f / lrun;
    int srow_q = b * SEQ + q0 + wid * 32 + l31;
    short* outp = AOb + (size_t)srow_q * DMODEL + h * DK;
    #pragma unroll
    for (int g = 0; g < 4; g++) {
        int d0 = 8 * g + 4 * hi;
        uint2 u;
        u.x = pk2(ot0[4 * g] * inv, ot0[4 * g + 1] * inv);
        u.y = pk2(ot0[4 * g + 2] * inv, ot0[4 * g + 3] * inv);
        *(uint2*)&outp[d0] = u;
        uint2 v2;
        v2.x = pk2(ot1[4 * g] * inv, ot1[4 * g + 1] * inv);
        v2.y = pk2(ot1[4 * g + 2] * inv, ot1[4 * g + 3] * inv);
        *(uint2*)&outp[32 + d0] = v2;
    }
}

extern "C" void kernel_launch(void* const* d_in, const int* in_sizes, int n_in,
                              void* d_out, int out_size, void* d_ws, size_t ws_size,
                              hipStream_t stream)
{
    const float* x  = (const float*)d_in[0];
    const float* Wq = (const float*)d_in[1];
    const float* bq = (const float*)d_in[2];
    const float* Wk = (const float*)d_in[3];
    const float* bk = (const float*)d_in[4];
    const float* Wv = (const float*)d_in[5];
    const float* bv = (const float*)d_in[6];
    const float* Wo = (const float*)d_in[7];
    const float* bo = (const float*)d_in[8];
    float* out = (float*)d_out;

    char* w = (char*)d_ws;
    short* xb    = (short*)w; w += (size_t)MTOT * DMODEL * 2;
    short* Wqkvt = (short*)w; w += (size_t)3 * DMODEL * DMODEL * 2;
    short* Wot   = (short*)w; w += (size_t)DMODEL * DMODEL * 2;
    short* Qb    = (short*)w; w += (size_t)MTOT * DMODEL * 2;
    short* Kb    = (short*)w; w += (size_t)MTOT * DMODEL * 2;
    short* Vtb   = (short*)w; w += (size_t)MTOT * DMODEL * 2;
    short* AOb   = (short*)w; w += (size_t)MTOT * DMODEL * 2;

    prep_kernel<<<NCVT + 4096, 256, 0, stream>>>(x, xb, Wq, Wk, Wv, Wo, Wqkvt, Wot);

    gemm_kernel<0><<<dim3(3 * DMODEL / 128, MTOT / 128), 256, 0, stream>>>(
        xb, Wqkvt, bq, bk, bv, Qb, Kb, Vtb, nullptr);

    attn_kernel<<<dim3(SEQ / 128 * NH * NB), 256, 0, stream>>>(Qb, Kb, Vtb, AOb);

    gemm_kernel<1><<<dim3(DMODEL / 128, MTOT / 128), 256, 0, stream>>>(
        AOb, Wot, bo, nullptr, nullptr, nullptr, nullptr, nullptr, out);
}

// Round 9
// 219.932 us; speedup vs baseline: 1.6147x; 1.6147x over previous
//
#include <hip/hip_runtime.h>

// MHA forward, bf16-MFMA pipeline.
// ws: xb(16M) | Wqkv_t(6M) | Wo_t(2M) | Q(16M) | K(16M) | Vt(16M) | AO(16M)

typedef short short8 __attribute__((ext_vector_type(8)));
typedef float f32x4 __attribute__((ext_vector_type(4)));
typedef float f32x16 __attribute__((ext_vector_type(16)));

#define DMODEL 1024
#define NH 16
#define DK 64
#define SEQ 2048
#define NB 4
#define MTOT (NB*SEQ)   // 8192
// 1/sqrt(dk) * log2(e)  — folded into K at projection time; softmax runs in exp2 domain
#define KSCALE 0.18033688f

__device__ __forceinline__ unsigned short f2bf(float f) {
    union { float f; unsigned u; } v; v.f = f;
    unsigned r = (v.u + 0x7FFFu + ((v.u >> 16) & 1u)) >> 16;  // RNE
    return (unsigned short)r;
}

__device__ __forceinline__ unsigned pk2(float a, float b) {
    unsigned r;
    asm("v_cvt_pk_bf16_f32 %0, %1, %2" : "=v"(r) : "v"(a), "v"(b));
    return r;
}

__device__ __forceinline__ float exp2a(float x) {
    float r; asm("v_exp_f32 %0, %1" : "=v"(r) : "v"(x)); return r;
}

__device__ __forceinline__ float max3a(float a, float b, float c) {
    float r; asm("v_max3_f32 %0, %1, %2, %3" : "=v"(r) : "v"(a), "v"(b), "v"(c)); return r;
}

// v_permlane32_swap_b32: vdst lanes 32-63 <-> vsrc lanes 0-31 (both modified)
__device__ __forceinline__ void plswap(unsigned &a, unsigned &b) {
    asm volatile("v_permlane32_swap_b32 %0, %1" : "+v"(a), "+v"(b));
}

// async global->LDS, 16B per lane; lds dest is wave-uniform base (+lane*16)
__device__ __forceinline__ void gload16(const short* g, short* l) {
    __builtin_amdgcn_global_load_lds(
        (const __attribute__((address_space(1))) unsigned*)(const void*)g,
        (__attribute__((address_space(3))) unsigned*)(void*)l,
        16, 0, 0);
}

__device__ __forceinline__ void vm4()   { asm volatile("s_waitcnt vmcnt(4)"   ::: "memory"); }
__device__ __forceinline__ void vm0()   { asm volatile("s_waitcnt vmcnt(0)"   ::: "memory"); }
__device__ __forceinline__ void lgkm0() { asm volatile("s_waitcnt lgkmcnt(0)" ::: "memory"); }

union Frag { short8 s8; unsigned u[4]; };

// ---------- fused prep: x fp32->bf16 convert + 4x W transpose ----------
#define NCVT (MTOT * DMODEL / 4 / 256)   // 8192
__global__ __launch_bounds__(256) void prep_kernel(
    const float* __restrict__ x, short* __restrict__ xb,
    const float* __restrict__ Wq, const float* __restrict__ Wk,
    const float* __restrict__ Wv, const float* __restrict__ Wo,
    short* __restrict__ Wqkvt, short* __restrict__ Wot)
{
    __shared__ float t[32][33];
    int bid = blockIdx.x;
    if (bid < NCVT) {
        int i = bid * 256 + threadIdx.x;
        float4 v = ((const float4*)x)[i];
        short4 o;
        o.x = (short)f2bf(v.x); o.y = (short)f2bf(v.y);
        o.z = (short)f2bf(v.z); o.w = (short)f2bf(v.w);
        ((short4*)xb)[i] = o;
        return;
    }
    int wb = bid - NCVT;                 // 0..4095
    int widx = wb >> 10, tile = wb & 1023;
    const float* W = (widx == 0) ? Wq : (widx == 1) ? Wk : (widx == 2) ? Wv : Wo;
    short* dst = (widx < 3) ? (Wqkvt + (size_t)widx * DMODEL * DMODEL) : Wot;
    int r0 = (tile >> 5) * 32, c0 = (tile & 31) * 32;
    int tr = threadIdx.x >> 3;
    int tc = (threadIdx.x & 7) * 4;
    float4 v = *(const float4*)&W[(r0 + tr) * DMODEL + c0 + tc];
    t[tr][tc + 0] = v.x; t[tr][tc + 1] = v.y; t[tr][tc + 2] = v.z; t[tr][tc + 3] = v.w;
    __syncthreads();
    short4 o;
    o.x = (short)f2bf(t[tc + 0][tr]);
    o.y = (short)f2bf(t[tc + 1][tr]);
    o.z = (short)f2bf(t[tc + 2][tr]);
    o.w = (short)f2bf(t[tc + 3][tr]);
    *(short4*)&dst[(c0 + tr) * DMODEL + r0 + tc] = o;
}

// ---------- 128x128 bf16 GEMM, counted-vmcnt pipeline, ring-3 LDS (48KB) ----------
// 32 half-phases (32 K-cols each). Phase H: ds_read slot H%3, stage H+2 into
// (H+2)%3, lgkm0+barrier (certifies slot H reads; protects ring reuse),
// 16 MFMA, vmcnt(4)+barrier (certifies stage H+1 landed, cross-wave).
// 48KB -> 3 blocks/CU (vs 64KB ring-4's 2): pipeline + occupancy combined.
template<int MODE>
__global__ __launch_bounds__(256) void gemm_kernel(
    const short* __restrict__ A, const short* __restrict__ Bt,
    const float* __restrict__ b0, const float* __restrict__ b1, const float* __restrict__ b2,
    short* __restrict__ Qb, short* __restrict__ Kb, short* __restrict__ Vtb,
    float* __restrict__ Cout)
{
    __shared__ __align__(16) short L[3][2][128 * 32];   // [slot][A/B][r*32+c] = 48 KB
    const int K = DMODEL;
    const int NHP = 2 * (K / 64);   // 32 half-phases
    int m0 = blockIdx.y * 128, n0 = blockIdx.x * 128;
    int tid = threadIdx.x, lane = tid & 63, wid = tid >> 6;
    int wm = (wid >> 1) * 64, wn = (wid & 1) * 64;

    // staging: lane covers row (lane>>2) of a 16-row band, 16B chunk (lane&3),
    // column pre-swizzled by ((row>>1)&3) = (lane>>3)&3 (inverse of read swizzle)
    int srowl = (lane >> 2);
    int scoll = ((lane & 3) ^ ((lane >> 3) & 3)) * 8;
    const short* aSrc = A + (size_t)(m0 + wid * 32 + srowl) * K + scoll;
    const short* bSrc = Bt + (size_t)(n0 + wid * 32 + srowl) * K + scoll;

    f32x4 acc[4][4];
    #pragma unroll
    for (int i = 0; i < 4; i++)
        #pragma unroll
        for (int j = 0; j < 4; j++) acc[i][j] = (f32x4){0.f, 0.f, 0.f, 0.f};

    // stage half-phase H (K-cols [H*32, H*32+32)) into slot H%3
    auto STAGE = [&](int H) {
        int sl = H % 3;
        const short* as = aSrc + H * 32;
        const short* bs = bSrc + H * 32;
        #pragma unroll
        for (int i = 0; i < 2; ++i) {
            gload16(as + (size_t)i * 16 * K, &L[sl][0][(wid * 32 + i * 16) * 32]);
            gload16(bs + (size_t)i * 16 * K, &L[sl][1][(wid * 32 + i * 16) * 32]);
        }
    };
    auto LDA = [&](int sl, short8* f) {
        #pragma unroll
        for (int m = 0; m < 4; m++) {
            int r = wm + m * 16 + (lane & 15);
            f[m] = *(const short8*)&L[sl][0][r * 32 + (((lane >> 4) ^ ((r >> 1) & 3)) * 8)];
        }
    };
    auto LDB = [&](int sl, short8* f) {
        #pragma unroll
        for (int n = 0; n < 4; n++) {
            int r = wn + n * 16 + (lane & 15);
            f[n] = *(const short8*)&L[sl][1][r * 32 + (((lane >> 4) ^ ((r >> 1) & 3)) * 8)];
        }
    };

    // prologue: stage halves 0,1; certify half 0 landed (own share), rendezvous
    STAGE(0);
    STAGE(1);
    vm4();
    __builtin_amdgcn_s_barrier();

    for (int H = 0; H < NHP; ++H) {
        int sl = H % 3;
        short8 af[4], bfv[4];
        LDA(sl, af); LDB(sl, bfv);
        if (H + 2 < NHP) STAGE(H + 2);
        lgkm0();
        __builtin_amdgcn_s_barrier();   // slot-sl reads certified; ring slot (H+2)%3 safe to land
        __builtin_amdgcn_s_setprio(1);
        #pragma unroll
        for (int i = 0; i < 4; i++)
            #pragma unroll
            for (int j = 0; j < 4; j++)
                acc[i][j] = __builtin_amdgcn_mfma_f32_16x16x32_bf16(af[i], bfv[j], acc[i][j], 0, 0, 0);
        __builtin_amdgcn_s_setprio(0);
        if (H + 2 < NHP)       { vm4(); __builtin_amdgcn_s_barrier(); }   // stage H+1 landed
        else if (H + 2 == NHP) { vm0(); __builtin_amdgcn_s_barrier(); }   // last stage landed
        // H == NHP-1: fall through to epilogue
    }

    #pragma unroll
    for (int i = 0; i < 4; i++) {
        #pragma unroll
        for (int j = 0; j < 4; j++) {
            int col = n0 + wn + j * 16 + (lane & 15);
            #pragma unroll
            for (int r = 0; r < 4; r++) {
                int row = m0 + wm + i * 16 + (lane >> 4) * 4 + r;
                float v = acc[i][j][r];
                if (MODE == 0) {
                    int seg = col >> 10, c = col & 1023;
                    const float* bp = (seg == 0) ? b0 : (seg == 1 ? b1 : b2);
                    v += bp[c];
                    if (seg == 1) v *= KSCALE;   // fold softmax scale*log2e into K
                    unsigned short bv = f2bf(v);
                    int hh = c >> 6, d = c & 63, bb = row >> 11, s = row & 2047;
                    if (seg == 0)      Qb [(((bb * NH + hh) * SEQ) + s) * DK + d] = (short)bv;
                    else if (seg == 1) Kb [(((bb * NH + hh) * SEQ) + s) * DK + d] = (short)bv;
                    else               Vtb[(((bb * NH + hh) * DK) + d) * SEQ + s] = (short)bv;
                } else {
                    Cout[row * DMODEL + col] = v + b0[col];
                }
            }
        }
    }
}

// ---------- flash attention (R4/R6-proven version, 106.6 us) ----------
// swapped-QK^T 32x32, exp2-domain softmax, 4 waves, 32 q/wave, KV tiles 64.
// Single-buffer LDS; T14 reg prefetch; write after barrier; 2 barriers/tile.
__global__ __launch_bounds__(256) void attn_kernel(
    const short* __restrict__ Qb, const short* __restrict__ Kb,
    const short* __restrict__ Vtb, short* __restrict__ AOb)
{
    __shared__ __align__(16) short Ks[64 * 64];
    __shared__ __align__(16) short Vs[64 * 64];
    char* ksb = (char*)Ks;
    char* vsb = (char*)Vs;

    int bid = blockIdx.x;                       // 0..1023
    int wk = (bid & 7) * 128 + (bid >> 3);      // XCD-contiguous work
    int qi = wk & 15, bh = wk >> 4;
    int h = bh & (NH - 1), b = bh >> 4;
    int q0 = qi * 128;

    int tid = threadIdx.x, lane = tid & 63, wid = tid >> 6;
    int hi = lane >> 5, l31 = lane & 31, l7 = lane & 7;
    const short* Qp = Qb + (size_t)bh * SEQ * DK;
    const short* Kp = Kb + (size_t)bh * SEQ * DK;
    const short* Vp = Vtb + (size_t)bh * DK * SEQ;

    // Q fragments (B-operand): lane holds Q[q=l31][ks*16+hi*8+j]
    short8 qf[4];
    #pragma unroll
    for (int ks = 0; ks < 4; ks++)
        qf[ks] = *(const short8*)&Qp[(q0 + wid * 32 + l31) * DK + ks * 16 + hi * 8];

    f32x16 ot0, ot1;
    #pragma unroll
    for (int r = 0; r < 16; r++) { ot0[r] = 0.f; ot1[r] = 0.f; }
    float mrun = -1e30f, lrun = 0.f;

    int srow = tid >> 3, ssl = tid & 7;   // staging: 256 threads x 2 chunks
    #pragma unroll
    for (int i = 0; i < 2; i++) {
        int row = srow + 32 * i;
        *(short8*)(ksb + ((row * 128 + ssl * 16) ^ ((row & 7) << 4))) =
            *(const short8*)&Kp[row * DK + ssl * 8];
        *(short8*)(vsb + ((row * 128 + ssl * 16) ^ ((row & 7) << 4))) =
            *(const short8*)&Vp[row * SEQ + ssl * 8];
    }
    __syncthreads();

    const int NT = SEQ / 64;
    for (int t = 0; t < NT; ++t) {
        // T14: prefetch next tile into regs (latency hides under compute)
        short8 nk[2], nv[2];
        if (t + 1 < NT) {
            int kv0n = (t + 1) * 64;
            #pragma unroll
            for (int i = 0; i < 2; i++) {
                int row = srow + 32 * i;
                nk[i] = *(const short8*)&Kp[(kv0n + row) * DK + ssl * 8];
                nv[i] = *(const short8*)&Vp[row * SEQ + kv0n + ssl * 8];
            }
        }

        // swapped QK^T: St[kv][q]
        f32x16 st0, st1;
        #pragma unroll
        for (int r = 0; r < 16; r++) { st0[r] = 0.f; st1[r] = 0.f; }
        __builtin_amdgcn_s_setprio(1);
        #pragma unroll
        for (int ks = 0; ks < 4; ks++) {
            short8 kf0 = *(const short8*)(ksb + ((l31 * 128 + ks * 32 + hi * 16) ^ (l7 << 4)));
            short8 kf1 = *(const short8*)(ksb + (((32 + l31) * 128 + ks * 32 + hi * 16) ^ (l7 << 4)));
            st0 = __builtin_amdgcn_mfma_f32_32x32x16_bf16(kf0, qf[ks], st0, 0, 0, 0);
            st1 = __builtin_amdgcn_mfma_f32_32x32x16_bf16(kf1, qf[ks], st1, 0, 0, 0);
        }
        __builtin_amdgcn_s_setprio(0);

        // row max via max3 tree (32 values -> 1), then lane-pair exchange
        float m8[8];
        #pragma unroll
        for (int i = 0; i < 8; i++) m8[i] = max3a(st0[i], st0[i + 8], st1[i]);
        float m4[4];
        #pragma unroll
        for (int i = 0; i < 4; i++) m4[i] = max3a(m8[i], m8[i + 4], st1[i + 8]);
        float m2a = max3a(m4[0], m4[2], st1[12]);
        float m2b = max3a(m4[1], m4[3], st1[13]);
        float mxv = max3a(m2a, m2b, st1[14]);
        mxv = fmaxf(mxv, st1[15]);
        float mt = fmaxf(mxv, __shfl_xor(mxv, 32, 64));

        // T13 defer-max (log2 domain, threshold 11 -> P bounded by 2^11)
        if (!__all(mt - mrun <= 11.0f)) {
            float mn = fmaxf(mrun, mt);
            float al = exp2a(mrun - mn);
            lrun *= al;
            #pragma unroll
            for (int r = 0; r < 16; r++) { ot0[r] *= al; ot1[r] *= al; }
            mrun = mn;
        }
        #pragma unroll
        for (int r = 0; r < 16; r++) {
            st0[r] = exp2a(st0[r] - mrun);
            st1[r] = exp2a(st1[r] - mrun);
        }
        float s16[16];
        #pragma unroll
        for (int r = 0; r < 16; r++) s16[r] = st0[r] + st1[r];
        #pragma unroll
        for (int s = 8; s > 0; s >>= 1)
            #pragma unroll
            for (int r = 0; r < 8; r++) if (r < s) s16[r] += s16[r + s];
        lrun += s16[0] + __shfl_xor(s16[0], 32, 64);

        // T12 repack: P -> bf16 B-fragments via cvt_pk + permlane32_swap
        unsigned w0[8], w1[8];
        #pragma unroll
        for (int m = 0; m < 4; m++) {
            w0[m * 2]     = pk2(st0[4 * m], st0[4 * m + 1]);
            w0[m * 2 + 1] = pk2(st0[4 * m + 2], st0[4 * m + 3]);
            w1[m * 2]     = pk2(st1[4 * m], st1[4 * m + 1]);
            w1[m * 2 + 1] = pk2(st1[4 * m + 2], st1[4 * m + 3]);
        }
        short8 pf[4];
        #pragma unroll
        for (int ks = 0; ks < 4; ks++) {
            unsigned a0 = (ks < 2) ? w0[4 * (ks & 1) + 0] : w1[4 * (ks & 1) + 0];
            unsigned b0_ = (ks < 2) ? w0[4 * (ks & 1) + 2] : w1[4 * (ks & 1) + 2];
            unsigned a1 = (ks < 2) ? w0[4 * (ks & 1) + 1] : w1[4 * (ks & 1) + 1];
            unsigned b1_ = (ks < 2) ? w0[4 * (ks & 1) + 3] : w1[4 * (ks & 1) + 3];
            plswap(a0, b0_);
            plswap(a1, b1_);
            Frag f;
            f.u[0] = a0; f.u[1] = a1; f.u[2] = b0_; f.u[3] = b1_;
            pf[ks] = f.s8;
        }

        // transposed PV: O^T[d][q] += V^T * P^T
        __builtin_amdgcn_s_setprio(1);
        #pragma unroll
        for (int ks = 0; ks < 4; ks++) {
            short8 vf0 = *(const short8*)(vsb + ((l31 * 128 + ks * 32 + hi * 16) ^ (l7 << 4)));
            short8 vf1 = *(const short8*)(vsb + (((32 + l31) * 128 + ks * 32 + hi * 16) ^ (l7 << 4)));
            ot0 = __builtin_amdgcn_mfma_f32_32x32x16_bf16(vf0, pf[ks], ot0, 0, 0, 0);
            ot1 = __builtin_amdgcn_mfma_f32_32x32x16_bf16(vf1, pf[ks], ot1, 0, 0, 0);
        }
        __builtin_amdgcn_s_setprio(0);

        __syncthreads();
        if (t + 1 < NT) {
            #pragma unroll
            for (int i = 0; i < 2; i++) {
                int row = srow + 32 * i;
                *(short8*)(ksb + ((row * 128 + ssl * 16) ^ ((row & 7) << 4))) = nk[i];
                *(short8*)(vsb + ((row * 128 + ssl * 16) ^ ((row & 7) << 4))) = nv[i];
            }
        }
        __syncthreads();
    }

    // epilogue: normalize + store O[q][d] bf16 into AOb[b*SEQ+s][h*64+d]
    float inv = 1.f / lrun;
    int srow_q = b * SEQ + q0 + wid * 32 + l31;
    short* outp = AOb + (size_t)srow_q * DMODEL + h * DK;
    #pragma unroll
    for (int g = 0; g < 4; g++) {
        int d0 = 8 * g + 4 * hi;
        uint2 u;
        u.x = pk2(ot0[4 * g] * inv, ot0[4 * g + 1] * inv);
        u.y = pk2(ot0[4 * g + 2] * inv, ot0[4 * g + 3] * inv);
        *(uint2*)&outp[d0] = u;
        uint2 v2;
        v2.x = pk2(ot1[4 * g] * inv, ot1[4 * g + 1] * inv);
        v2.y = pk2(ot1[4 * g + 2] * inv, ot1[4 * g + 3] * inv);
        *(uint2*)&outp[32 + d0] = v2;
    }
}

extern "C" void kernel_launch(void* const* d_in, const int* in_sizes, int n_in,
                              void* d_out, int out_size, void* d_ws, size_t ws_size,
                              hipStream_t stream)
{
    const float* x  = (const float*)d_in[0];
    const float* Wq = (const float*)d_in[1];
    const float* bq = (const float*)d_in[2];
    const float* Wk = (const float*)d_in[3];
    const float* bk = (const float*)d_in[4];
    const float* Wv = (const float*)d_in[5];
    const float* bv = (const float*)d_in[6];
    const float* Wo = (const float*)d_in[7];
    const float* bo = (const float*)d_in[8];
    float* out = (float*)d_out;

    char* w = (char*)d_ws;
    short* xb    = (short*)w; w += (size_t)MTOT * DMODEL * 2;
    short* Wqkvt = (short*)w; w += (size_t)3 * DMODEL * DMODEL * 2;
    short* Wot   = (short*)w; w += (size_t)DMODEL * DMODEL * 2;
    short* Qb    = (short*)w; w += (size_t)MTOT * DMODEL * 2;
    short* Kb    = (short*)w; w += (size_t)MTOT * DMODEL * 2;
    short* Vtb   = (short*)w; w += (size_t)MTOT * DMODEL * 2;
    short* AOb   = (short*)w; w += (size_t)MTOT * DMODEL * 2;

    prep_kernel<<<NCVT + 4096, 256, 0, stream>>>(x, xb, Wq, Wk, Wv, Wo, Wqkvt, Wot);

    gemm_kernel<0><<<dim3(3 * DMODEL / 128, MTOT / 128), 256, 0, stream>>>(
        xb, Wqkvt, bq, bk, bv, Qb, Kb, Vtb, nullptr);

    attn_kernel<<<dim3(SEQ / 128 * NH * NB), 256, 0, stream>>>(Qb, Kb, Vtb, AOb);

    gemm_kernel<1><<<dim3(DMODEL / 128, MTOT / 128), 256, 0, stream>>>(
        AOb, Wot, bo, nullptr, nullptr, nullptr, nullptr, nullptr, out);
}